// Round 13
// baseline (205.945 us; speedup 1.0000x reference)
//
#include <hip/hip_runtime.h>
#include <stdint.h>

// HilbertSerialization: stable argsort of 26-bit Hilbert+batch keys.
// 3 passes LSD radix (9,9,8 bits), reduce-then-scan (R11 skeleton: proven).
// R13: the per-digit scan over blocks is folded into genkeys/hist kernels:
// every block takes an arrival ticket (device atomicAdd, one per BLOCK --
// the R4-proven release/acquire protocol, NOT per-element); the last 128
// arrivers (already resident -> no deadlock) spin until all rows are
// published, then scan 4 columns each. Dispatches 10 -> 7.
// Dataflow: genkeys(+scan0) -> scatter0 -> hist1(+scan1) -> scatter1
//   -> hist2(+scan2) -> scatter2 -> d_out.

#define THREADS 512               // genkeys / hist blocks
#define SCTH 1024                 // scatter block threads
#define SWAVES (SCTH / 64)        // 16
#define TILE 4096                 // elements per block, passes 0/1
#define TILE2 8192                // elements per block, pass 2
#define IDX_BITS 22
#define IDX_MASK 0x3FFFFFu

// XCD-contiguous bijective tile swizzle: consecutive tiles -> same XCD L2.
__device__ __forceinline__ int tile_of(int bid, int nwg) {
  int q = nwg >> 3, r = nwg & 7;
  int x = bid & 7, k = bid >> 3;
  return x * q + (x < r ? x : r) + k;
}

// ---------------- Hilbert key (Skilling transpose algorithm, DEPTH=8) --------
__device__ __forceinline__ uint32_t hilbert_code(uint32_t x, uint32_t y, uint32_t z) {
  uint32_t X0 = x & 255u, X1 = y & 255u, X2 = z & 255u;
#pragma unroll
  for (int p = 7; p >= 0; --p) {
    uint32_t low = (1u << p) - 1u;
    uint32_t f0 = (uint32_t)-(int)((X0 >> p) & 1u);
    X0 ^= (low & f0);
    uint32_t f1 = (uint32_t)-(int)((X1 >> p) & 1u);
    uint32_t t1 = ((X0 ^ X1) & low) & ~f1;
    X0 ^= (low & f1) ^ t1;
    X1 ^= t1;
    uint32_t f2 = (uint32_t)-(int)((X2 >> p) & 1u);
    uint32_t t2 = ((X0 ^ X2) & low) & ~f2;
    X0 ^= (low & f2) ^ t2;
    X2 ^= t2;
  }
  uint32_t G = 0;
#pragma unroll
  for (int k = 0; k < 8; ++k) {
    int p = 7 - k;
    G |= ((X0 >> p) & 1u) << (23 - 3 * k);
    G |= ((X1 >> p) & 1u) << (22 - 3 * k);
    G |= ((X2 >> p) & 1u) << (21 - 3 * k);
  }
  G ^= G >> 16; G ^= G >> 8; G ^= G >> 4; G ^= G >> 2; G ^= G >> 1;
  return G & 0xFFFFFFu;
}

// ---- column scan helper: exclusive scan of hist column d over nrows -------
// (nrows <= blockDim.x = 512; 8 waves). Writes scan in place + dt[d] = total.
__device__ __forceinline__ void scan_col(int* __restrict__ hist, int* __restrict__ dt,
                                         int nrows, int nbins, int d, int t,
                                         int* wsum) {
  __syncthreads();                       // protect wsum reuse across calls
  int wave = t >> 6, lane = t & 63;
  int vv = (t < nrows) ? hist[(size_t)t * nbins + d] : 0;
  int x = vv;
#pragma unroll
  for (int off = 1; off < 64; off <<= 1) {
    int n = __shfl_up(x, off);
    if (lane >= off) x += n;
  }
  if (lane == 63) wsum[wave] = x;
  __syncthreads();
  int pre = 0;
  for (int w = 0; w < wave; ++w) pre += wsum[w];
  if (t < nrows) hist[(size_t)t * nbins + d] = pre + x - vv;   // exclusive
  if (t == 0) {
    int tot = 0;
    for (int w = 0; w < 8; ++w) tot += wsum[w];
    dt[d] = tot;
  }
}

// ---- tail-scan: ticket + last-NSCAN-arrivers scan CPB=4 columns each -------
template <int NBINS>
__device__ __forceinline__ void ticket_and_scan(
    int* __restrict__ hist, int* __restrict__ dt, int* __restrict__ done,
    int t, int* wsum, int* sh_ticket) {
  constexpr int NSCAN = NBINS / 4;
  int nbG = gridDim.x;
  __syncthreads();                      // all row stores issued
  if (t == 0) {
    __threadfence();                    // release: write back XCD L2
    *sh_ticket = atomicAdd(done, 1);    // device-scope arrival ticket
  }
  __syncthreads();
  int ticket = *sh_ticket;
  if (ticket >= nbG - NSCAN) {
    if (t == 0) {
      while (__hip_atomic_load(done, __ATOMIC_RELAXED, __HIP_MEMORY_SCOPE_AGENT) < nbG)
        __builtin_amdgcn_s_sleep(2);
    }
    __syncthreads();
    __threadfence();                    // acquire: invalidate stale L1/L2
    int rank = ticket - (nbG - NSCAN);
#pragma unroll
    for (int c = 0; c < 4; ++c)
      scan_col(hist, dt, nbG, NBINS, rank * 4 + c, t, wsum);
  }
}

// ---------------- key generation + pass-0 histogram + fused scan0 -----------
__global__ __launch_bounds__(THREADS) void genkeys_hist(
    const int4* __restrict__ coords, const void* __restrict__ ss,
    const int* __restrict__ shifts, uint32_t* __restrict__ keys0,
    int* __restrict__ hist, int* __restrict__ dt, int* __restrict__ done, int N) {
  __shared__ int lh[512];
  __shared__ int wsum[8];
  __shared__ int sh_ticket;
  int t = threadIdx.x, b = tile_of(blockIdx.x, gridDim.x);
  lh[t] = 0;

  const int* p32 = (const int*)ss;
  int D, H, W;
  if (p32[1] == 0) { const long long* p64 = (const long long*)ss;
    D = (int)p64[0]; H = (int)p64[1]; W = (int)p64[2]; }
  else { D = p32[0]; H = p32[1]; W = p32[2]; }
  int sflag = shifts[0];
  int sx = sflag ? 15 : 0, sy = sflag ? 15 : 0, sz = sflag ? 4 : 0;
  bool wp2 = (W & (W - 1)) == 0, hp2 = (H & (H - 1)) == 0, dp2 = (D & (D - 1)) == 0;
  __syncthreads();

#pragma unroll
  for (int r = 0; r < TILE / THREADS; ++r) {
    int idx = b * TILE + r * THREADS + t;
    if (idx < N) {
      int4 c = coords[idx];            // (b, z, y, x)
      uint32_t bb = (uint32_t)c.x;
      int zz = c.y + sz, yy = c.z + sy, xx = c.w + sx;
      uint32_t z = (uint32_t)(dp2 ? (zz & (D - 1)) : (zz % D));
      uint32_t y = (uint32_t)(hp2 ? (yy & (H - 1)) : (yy % H));
      uint32_t x = (uint32_t)(wp2 ? (xx & (W - 1)) : (xx % W));
      uint32_t code = hilbert_code(x, y, z) | (bb << 24);
      keys0[idx] = code;
      atomicAdd(&lh[code & 511u], 1);
    }
  }
  __syncthreads();
  hist[(size_t)b * 512 + t] = lh[t];   // [block][digit]: coalesced
  ticket_and_scan<512>(hist, dt, done, t, wsum, &sh_ticket);
}

// ---------------- per-pass histogram + fused scan, uint4-vectorized ---------
template <int SHIFT, int NB, int TB>
__global__ __launch_bounds__(THREADS) void hist_kernel(
    const uint32_t* __restrict__ keys, int* __restrict__ hist,
    int* __restrict__ dt, int* __restrict__ done, int N) {
  __shared__ int lh[NB];
  __shared__ int wsum[8];
  __shared__ int sh_ticket;
  int t = threadIdx.x, b = tile_of(blockIdx.x, gridDim.x);
  if (t < NB) lh[t] = 0;
  __syncthreads();
#pragma unroll
  for (int r = 0; r < TB / THREADS / 4; ++r) {
    int base = b * TB + (r * THREADS + t) * 4;
    if (base + 3 < N) {
      uint4 k = *(const uint4*)(keys + base);
      atomicAdd(&lh[(k.x >> SHIFT) & (NB - 1)], 1);
      atomicAdd(&lh[(k.y >> SHIFT) & (NB - 1)], 1);
      atomicAdd(&lh[(k.z >> SHIFT) & (NB - 1)], 1);
      atomicAdd(&lh[(k.w >> SHIFT) & (NB - 1)], 1);
    } else {
      for (int u = 0; u < 4; ++u)
        if (base + u < N) atomicAdd(&lh[(keys[base + u] >> SHIFT) & (NB - 1)], 1);
    }
  }
  __syncthreads();
  if (t < NB) hist[(size_t)b * NB + t] = lh[t];
  ticket_and_scan<NB>(hist, dt, done, t, wsum, &sh_ticket);
}

// ---------------- stable scatter with LDS staging (16 waves, R11) -----------
// MODE 0: in keys0 (bits 0..8), val=idx recomputed -> keys1[], vals1[]
// MODE 1: in keys1+vals1 (bits 9..17)  -> packed (digit2<<22|idx)
// MODE 2: in packed (bits 22..29), TILE2 -> final idx to d_out
// Stability within block: (wave, round, lane) == original index order.
template <int MODE>
__global__ __launch_bounds__(SCTH) void scatter_kernel(
    const uint32_t* __restrict__ in0, const uint32_t* __restrict__ in1,
    uint32_t* __restrict__ out0, uint32_t* __restrict__ out1,
    const int* __restrict__ hist, const int* __restrict__ digitTotals, int N) {
  constexpr int NB = (MODE == 2) ? 256 : 512;
  constexpr int RB = (MODE == 2) ? 8 : 9;
  constexpr int SHIFT = (MODE == 0) ? 0 : (MODE == 1) ? 9 : 22;
  constexpr int TB = (MODE == 2) ? TILE2 : TILE;
  constexpr int RNDS = TB / SCTH;                  // 4 or 8
  constexpr int CH = TB / SWAVES;                  // 256 or 512
  __shared__ uint64_t sbuf[TB <= 4096 ? TB : TB / 2];        // 32 KB
  __shared__ __align__(16) unsigned short cnt[SWAVES][NB];   // 16 / 8 KB
  int t = threadIdx.x, b = tile_of(blockIdx.x, gridDim.x);
  int wave = t >> 6, lane = t & 63;

  int histv = 0, dt = 0;
  if (t < NB) {
    histv = hist[(size_t)b * NB + t];   // coalesced row
    dt = digitTotals[t];
  }
  for (int i = t; i < SWAVES * NB; i += SCTH) ((unsigned short*)cnt)[i] = 0;
  __syncthreads();

  uint32_t kR[RNDS];
  uint32_t vR[(MODE == 1) ? RNDS : 1];  // only MODE 1 carries a payload
  int drR[RNDS];                        // digit | rankInChunk<<RB, -1 invalid
  uint64_t ltm = (1ull << lane) - 1ull;
  int chunk0 = b * TB + wave * CH;

  // ---- prefetch: independent global loads in flight ----
#pragma unroll
  for (int r = 0; r < RNDS; ++r) {
    int idx = chunk0 + r * 64 + lane;
    bool valid = idx < N;
    kR[r] = valid ? in0[idx] : 0u;
    if (MODE == 1) vR[r] = valid ? in1[idx] : 0u;
  }

  // ---- phase A: wave-private stable ranking (no barriers) ----
#pragma unroll
  for (int r = 0; r < RNDS; ++r) {
    int idx = chunk0 + r * 64 + lane;
    bool valid = idx < N;
    int digit = (int)((kR[r] >> SHIFT) & (NB - 1));
    uint64_t eq = __ballot(valid);
#pragma unroll
    for (int bit = 0; bit < RB; ++bit) {
      uint64_t m = __ballot((digit >> bit) & 1);
      eq &= ((digit >> bit) & 1) ? m : ~m;
    }
    int waveRank = __popcll(eq & ltm);
    int cntW = __popcll(eq);
    int prior = cnt[wave][digit];       // wave-private row: no race
    drR[r] = valid ? (digit | ((prior + waveRank) << RB)) : -1;
    if (valid && waveRank == 0) cnt[wave][digit] = (unsigned short)(prior + cntW);
  }
  __syncthreads();

  // ---- bin totals + int2 shuffle scan (scratch = dead sbuf) ----
  int2* wt = (int2*)sbuf;
  int tot = 0, adjv = 0;
  int2 v = make_int2(0, 0);
  if (t < NB) {
#pragma unroll
    for (int w = 0; w < SWAVES; ++w) tot += cnt[w][t];
    v = make_int2(tot, dt);
#pragma unroll
    for (int off = 1; off < 64; off <<= 1) {
      int nx = __shfl_up(v.x, off), ny = __shfl_up(v.y, off);
      if (lane >= off) { v.x += nx; v.y += ny; }
    }
    if (lane == 63) wt[wave] = v;
  }
  __syncthreads();
  if (t < NB) {
    int2 pre = make_int2(0, 0);
    for (int w = 0; w < wave; ++w) { pre.x += wt[w].x; pre.y += wt[w].y; }
    int ds = pre.x + v.x - tot;         // exclusive in-block digit start
    adjv = histv + (pre.y + v.y - dt) - ds;   // globalBase - digitStart
    int run = ds;                        // fold ds into cnt rows: slot base
#pragma unroll
    for (int w = 0; w < SWAVES; ++w) {
      int x = cnt[w][t];
      cnt[w][t] = (unsigned short)run;
      run += x;
    }
  }
  __syncthreads();

  // ---- stage into LDS in digit-sorted order ----
#pragma unroll
  for (int r = 0; r < RNDS; ++r) {
    int dr = drR[r];
    if (dr >= 0) {
      int digit = dr & (NB - 1);
      int rnk = dr >> RB;
      int slot = (int)cnt[wave][digit] + rnk;
      if (MODE == 0) {
        uint32_t idxv = (uint32_t)(chunk0 + r * 64 + lane);  // implicit val
        sbuf[slot] = ((uint64_t)idxv << 32) | kR[r];
      } else if (MODE == 1) {
        sbuf[slot] = ((uint64_t)vR[r] << 32) | kR[r];
      } else {
        ((uint32_t*)sbuf)[slot] = kR[r];
      }
    }
  }
  __syncthreads();

  // ---- cnt is dead: reuse as adjArr ----
  int* adjArr = (int*)cnt;
  if (t < NB) adjArr[t] = adjv;
  __syncthreads();

  // ---- write out sequentially: digit runs are contiguous ----
  int validCount = min(TB, N - b * TB);
#pragma unroll
  for (int j = 0; j < RNDS; ++j) {
    int i = j * SCTH + t;
    if (i < validCount) {
      if (MODE == 0) {
        uint64_t kv = sbuf[i];
        uint32_t key = (uint32_t)kv;
        int pos = adjArr[key & 511u] + i;
        out0[pos] = key;
        out1[pos] = (uint32_t)(kv >> 32);
      } else if (MODE == 1) {
        uint64_t kv = sbuf[i];
        uint32_t key = (uint32_t)kv, idxv = (uint32_t)(kv >> 32);
        int pos = adjArr[(key >> 9) & 511u] + i;
        out0[pos] = ((key >> 18) << IDX_BITS) | idxv;   // digit2<<22 | idx
      } else {
        uint32_t p = ((uint32_t*)sbuf)[i];
        int pos = adjArr[(p >> IDX_BITS) & 255u] + i;
        out0[pos] = p & IDX_MASK;
      }
    }
  }
}

// ---------------- launch ----------------
extern "C" void kernel_launch(void* const* d_in, const int* in_sizes, int n_in,
                              void* d_out, int out_size, void* d_ws, size_t ws_size,
                              hipStream_t stream) {
  const int4* coords = (const int4*)d_in[0];
  const void* ss = d_in[1];
  const int* shifts = (const int*)d_in[2];
  int N = in_sizes[0] / 4;
  int nblocks = (N + TILE - 1) / TILE;       // passes 0/1 tiles (489)
  int nblocks2 = (N + TILE2 - 1) / TILE2;    // pass-2 tiles (245)

  char* ws = (char*)d_ws;
  size_t off = 0;
  auto alloc = [&](size_t bytes) -> void* {
    void* p = ws + off;
    off += (bytes + 255) & ~(size_t)255;
    return p;
  };
  uint32_t* keys0 = (uint32_t*)alloc((size_t)N * 4);
  uint32_t* keys1 = (uint32_t*)alloc((size_t)N * 4);
  uint32_t* vals1 = (uint32_t*)alloc((size_t)N * 4);
  uint32_t* packd = (uint32_t*)alloc((size_t)N * 4);
  int*      hist  = (int*)alloc((size_t)512 * nblocks * 4);
  int*      dt    = (int*)alloc(512 * 4);
  int*      done  = (int*)alloc(256);        // done[0..2] arrival counters

  hipMemsetAsync(done, 0, 256, stream);      // must be zero every call

  // pass 0 (bits 0..8, 512 bins): keys only; vals implicit; scan0 fused
  genkeys_hist<<<nblocks, THREADS, 0, stream>>>(coords, ss, shifts, keys0,
                                                hist, dt, done + 0, N);
  scatter_kernel<0><<<nblocks, SCTH, 0, stream>>>(
      keys0, nullptr, keys1, vals1, hist, dt, N);

  // pass 1 (bits 9..17, 512 bins): packed (digit2<<22 | idx); scan1 fused
  hist_kernel<9, 512, TILE><<<nblocks, THREADS, 0, stream>>>(keys1, hist, dt,
                                                             done + 1, N);
  scatter_kernel<1><<<nblocks, SCTH, 0, stream>>>(
      keys1, vals1, packd, nullptr, hist, dt, N);

  // pass 2 (packed bits 22..29, 256 bins, TILE2=8192): scan2 fused
  hist_kernel<22, 256, TILE2><<<nblocks2, THREADS, 0, stream>>>(packd, hist, dt,
                                                                done + 2, N);
  scatter_kernel<2><<<nblocks2, SCTH, 0, stream>>>(
      packd, nullptr, (uint32_t*)d_out, nullptr, hist, dt, N);
}

// Round 14
// 78.979 us; speedup vs baseline: 2.6076x; 2.6076x over previous
//
#include <hip/hip_runtime.h>
#include <stdint.h>

// HilbertSerialization: stable argsort of 26-bit Hilbert+batch keys.
// 3 passes LSD radix (9,9,8 bits), reduce-then-scan (R11 skeleton, proven).
// R14: pass0 -> pass1 hand-off is AoS (idx<<32|key) uint64 pairs: scatter0
// writes one 8B store per element (full 64B digit runs, half the stores);
// scatter1 loads one 8B pair; hist1 reads pairs via uint4 (2 keys / 16B).
// Dataflow: genkeys -> keys0 -> scatter0 -> pairs1 (AoS 8B)
//   -> scatter1 -> packed (digit2<<22|idx) -> scatter2 -> d_out.

#define THREADS 512               // genkeys / hist / scan blocks
#define SCTH 1024                 // scatter block threads
#define SWAVES (SCTH / 64)        // 16
#define TILE 4096                 // elements per block, passes 0/1
#define TILE2 8192                // elements per block, pass 2
#define IDX_BITS 22
#define IDX_MASK 0x3FFFFFu

// XCD-contiguous bijective tile swizzle: consecutive tiles -> same XCD L2.
__device__ __forceinline__ int tile_of(int bid, int nwg) {
  int q = nwg >> 3, r = nwg & 7;
  int x = bid & 7, k = bid >> 3;
  return x * q + (x < r ? x : r) + k;
}

// ---------------- Hilbert key (Skilling transpose algorithm, DEPTH=8) --------
__device__ __forceinline__ uint32_t hilbert_code(uint32_t x, uint32_t y, uint32_t z) {
  uint32_t X0 = x & 255u, X1 = y & 255u, X2 = z & 255u;
#pragma unroll
  for (int p = 7; p >= 0; --p) {
    uint32_t low = (1u << p) - 1u;
    uint32_t f0 = (uint32_t)-(int)((X0 >> p) & 1u);
    X0 ^= (low & f0);
    uint32_t f1 = (uint32_t)-(int)((X1 >> p) & 1u);
    uint32_t t1 = ((X0 ^ X1) & low) & ~f1;
    X0 ^= (low & f1) ^ t1;
    X1 ^= t1;
    uint32_t f2 = (uint32_t)-(int)((X2 >> p) & 1u);
    uint32_t t2 = ((X0 ^ X2) & low) & ~f2;
    X0 ^= (low & f2) ^ t2;
    X2 ^= t2;
  }
  uint32_t G = 0;
#pragma unroll
  for (int k = 0; k < 8; ++k) {
    int p = 7 - k;
    G |= ((X0 >> p) & 1u) << (23 - 3 * k);
    G |= ((X1 >> p) & 1u) << (22 - 3 * k);
    G |= ((X2 >> p) & 1u) << (21 - 3 * k);
  }
  G ^= G >> 16; G ^= G >> 8; G ^= G >> 4; G ^= G >> 2; G ^= G >> 1;
  return G & 0xFFFFFFu;
}

// ---------------- key generation fused with pass-0 histogram -----------------
__global__ __launch_bounds__(THREADS) void genkeys_hist(
    const int4* __restrict__ coords, const void* __restrict__ ss,
    const int* __restrict__ shifts, uint32_t* __restrict__ keys0,
    int* __restrict__ hist, int N) {
  __shared__ int lh[512];
  int t = threadIdx.x, b = tile_of(blockIdx.x, gridDim.x);
  lh[t] = 0;

  const int* p32 = (const int*)ss;
  int D, H, W;
  if (p32[1] == 0) { const long long* p64 = (const long long*)ss;
    D = (int)p64[0]; H = (int)p64[1]; W = (int)p64[2]; }
  else { D = p32[0]; H = p32[1]; W = p32[2]; }
  int sflag = shifts[0];
  int sx = sflag ? 15 : 0, sy = sflag ? 15 : 0, sz = sflag ? 4 : 0;
  bool wp2 = (W & (W - 1)) == 0, hp2 = (H & (H - 1)) == 0, dp2 = (D & (D - 1)) == 0;
  __syncthreads();

#pragma unroll
  for (int r = 0; r < TILE / THREADS; ++r) {
    int idx = b * TILE + r * THREADS + t;
    if (idx < N) {
      int4 c = coords[idx];            // (b, z, y, x)
      uint32_t bb = (uint32_t)c.x;
      int zz = c.y + sz, yy = c.z + sy, xx = c.w + sx;
      uint32_t z = (uint32_t)(dp2 ? (zz & (D - 1)) : (zz % D));
      uint32_t y = (uint32_t)(hp2 ? (yy & (H - 1)) : (yy % H));
      uint32_t x = (uint32_t)(wp2 ? (xx & (W - 1)) : (xx % W));
      uint32_t code = hilbert_code(x, y, z) | (bb << 24);
      keys0[idx] = code;
      atomicAdd(&lh[code & 511u], 1);
    }
  }
  __syncthreads();
  hist[(size_t)b * 512 + t] = lh[t];   // [block][digit]: coalesced
}

// ---------------- pass-1 histogram over AoS pairs (2 keys per uint4) --------
__global__ __launch_bounds__(THREADS) void hist_pairs(
    const uint64_t* __restrict__ pairs, int* __restrict__ hist, int N) {
  __shared__ int lh[512];
  int t = threadIdx.x, b = tile_of(blockIdx.x, gridDim.x);
  lh[t] = 0;
  __syncthreads();
#pragma unroll
  for (int r = 0; r < TILE / THREADS / 2; ++r) {
    int e = b * TILE + (r * THREADS + t) * 2;
    if (e + 1 < N) {
      uint4 k = *(const uint4*)(pairs + e);          // 2 pairs: keys in .x,.z
      atomicAdd(&lh[(k.x >> 9) & 511u], 1);
      atomicAdd(&lh[(k.z >> 9) & 511u], 1);
    } else {
      for (int u = 0; u < 2; ++u)
        if (e + u < N) atomicAdd(&lh[((uint32_t)pairs[e + u] >> 9) & 511u], 1);
    }
  }
  __syncthreads();
  hist[(size_t)b * 512 + t] = lh[t];
}

// ---------------- pass-2 histogram over packd, uint4-vectorized -------------
__global__ __launch_bounds__(THREADS) void hist_packd(
    const uint32_t* __restrict__ keys, int* __restrict__ hist, int N) {
  __shared__ int lh[256];
  int t = threadIdx.x, b = tile_of(blockIdx.x, gridDim.x);
  if (t < 256) lh[t] = 0;
  __syncthreads();
#pragma unroll
  for (int r = 0; r < TILE2 / THREADS / 4; ++r) {
    int base = b * TILE2 + (r * THREADS + t) * 4;
    if (base + 3 < N) {
      uint4 k = *(const uint4*)(keys + base);
      atomicAdd(&lh[(k.x >> 22) & 255u], 1);
      atomicAdd(&lh[(k.y >> 22) & 255u], 1);
      atomicAdd(&lh[(k.z >> 22) & 255u], 1);
      atomicAdd(&lh[(k.w >> 22) & 255u], 1);
    } else {
      for (int u = 0; u < 4; ++u)
        if (base + u < N) atomicAdd(&lh[(keys[base + u] >> 22) & 255u], 1);
    }
  }
  __syncthreads();
  if (t < 256) hist[(size_t)b * 256 + t] = lh[t];
}

// ---- per digit: exclusive scan over blocks (in place), total out -----------
__global__ __launch_bounds__(512) void scan_blocks(
    int* __restrict__ hist, int* __restrict__ digitTotals, int nblocks, int nbins) {
  __shared__ int wsum[8];
  int d = blockIdx.x, t = threadIdx.x, wave = t >> 6, lane = t & 63;
  int carry = 0;
  for (int start = 0; start < nblocks; start += 512) {
    int i = start + t;
    int vv = (i < nblocks) ? hist[(size_t)i * nbins + d] : 0;
    int x = vv;
#pragma unroll
    for (int off = 1; off < 64; off <<= 1) {
      int n = __shfl_up(x, off);
      if (lane >= off) x += n;
    }
    if (lane == 63) wsum[wave] = x;
    __syncthreads();
    int pre = 0;
    for (int w = 0; w < wave; ++w) pre += wsum[w];
    if (i < nblocks) hist[(size_t)i * nbins + d] = carry + pre + x - vv;
    int tot = 0;
    for (int w = 0; w < 8; ++w) tot += wsum[w];
    __syncthreads();
    carry += tot;
  }
  if (t == 0) digitTotals[d] = carry;
}

// ---------------- stable scatter with LDS staging (16 waves) ----------------
// MODE 0: in32=keys0 (bits 0..8), val=idx implicit -> out64=pairs1 (AoS)
// MODE 1: in64=pairs1 (bits 9..17 of low word)    -> out32=packd (d2<<22|idx)
// MODE 2: in32=packd (bits 22..29), TILE2         -> out32=d_out (final idx)
// Stability within block: (wave, round, lane) == original index order.
template <int MODE>
__global__ __launch_bounds__(SCTH) void scatter_kernel(
    const uint32_t* __restrict__ in32, const uint64_t* __restrict__ in64,
    uint32_t* __restrict__ out32, uint64_t* __restrict__ out64,
    const int* __restrict__ hist, const int* __restrict__ digitTotals, int N) {
  constexpr int NB = (MODE == 2) ? 256 : 512;
  constexpr int RB = (MODE == 2) ? 8 : 9;
  constexpr int SHIFT = (MODE == 0) ? 0 : (MODE == 1) ? 9 : 22;
  constexpr int TB = (MODE == 2) ? TILE2 : TILE;
  constexpr int RNDS = TB / SCTH;                  // 4 or 8
  constexpr int CH = TB / SWAVES;                  // 256 or 512
  __shared__ uint64_t sbuf[TB <= 4096 ? TB : TB / 2];        // 32 KB
  __shared__ __align__(16) unsigned short cnt[SWAVES][NB];   // 16 / 8 KB
  int t = threadIdx.x, b = tile_of(blockIdx.x, gridDim.x);
  int wave = t >> 6, lane = t & 63;

  int histv = 0, dt = 0;
  if (t < NB) {
    histv = hist[(size_t)b * NB + t];   // coalesced row
    dt = digitTotals[t];
  }
  for (int i = t; i < SWAVES * NB; i += SCTH) ((unsigned short*)cnt)[i] = 0;
  __syncthreads();

  uint64_t kvR[RNDS];
  int drR[RNDS];                        // digit | rankInChunk<<RB, -1 invalid
  uint64_t ltm = (1ull << lane) - 1ull;
  int chunk0 = b * TB + wave * CH;

  // ---- prefetch: independent global loads in flight ----
#pragma unroll
  for (int r = 0; r < RNDS; ++r) {
    int idx = chunk0 + r * 64 + lane;
    bool valid = idx < N;
    if (MODE == 0)
      kvR[r] = ((uint64_t)(uint32_t)idx << 32) | (valid ? in32[idx] : 0u);
    else if (MODE == 1)
      kvR[r] = valid ? in64[idx] : 0ull;
    else
      kvR[r] = valid ? in32[idx] : 0u;
  }

  // ---- phase A: wave-private stable ranking (no barriers) ----
#pragma unroll
  for (int r = 0; r < RNDS; ++r) {
    int idx = chunk0 + r * 64 + lane;
    bool valid = idx < N;
    int digit = (int)(((uint32_t)kvR[r] >> SHIFT) & (NB - 1));
    uint64_t eq = __ballot(valid);
#pragma unroll
    for (int bit = 0; bit < RB; ++bit) {
      uint64_t m = __ballot((digit >> bit) & 1);
      eq &= ((digit >> bit) & 1) ? m : ~m;
    }
    int waveRank = __popcll(eq & ltm);
    int cntW = __popcll(eq);
    int prior = cnt[wave][digit];       // wave-private row: no race
    drR[r] = valid ? (digit | ((prior + waveRank) << RB)) : -1;
    if (valid && waveRank == 0) cnt[wave][digit] = (unsigned short)(prior + cntW);
  }
  __syncthreads();

  // ---- bin totals + int2 shuffle scan (scratch = dead sbuf) ----
  int2* wt = (int2*)sbuf;
  int tot = 0, adjv = 0;
  int2 v = make_int2(0, 0);
  if (t < NB) {
#pragma unroll
    for (int w = 0; w < SWAVES; ++w) tot += cnt[w][t];
    v = make_int2(tot, dt);
#pragma unroll
    for (int off = 1; off < 64; off <<= 1) {
      int nx = __shfl_up(v.x, off), ny = __shfl_up(v.y, off);
      if (lane >= off) { v.x += nx; v.y += ny; }
    }
    if (lane == 63) wt[wave] = v;
  }
  __syncthreads();
  if (t < NB) {
    int2 pre = make_int2(0, 0);
    for (int w = 0; w < wave; ++w) { pre.x += wt[w].x; pre.y += wt[w].y; }
    int ds = pre.x + v.x - tot;         // exclusive in-block digit start
    adjv = histv + (pre.y + v.y - dt) - ds;   // globalBase - digitStart
    int run = ds;                        // fold ds into cnt rows: slot base
#pragma unroll
    for (int w = 0; w < SWAVES; ++w) {
      int x = cnt[w][t];
      cnt[w][t] = (unsigned short)run;
      run += x;
    }
  }
  __syncthreads();

  // ---- stage into LDS in digit-sorted order ----
#pragma unroll
  for (int r = 0; r < RNDS; ++r) {
    int dr = drR[r];
    if (dr >= 0) {
      int digit = dr & (NB - 1);
      int rnk = dr >> RB;
      int slot = (int)cnt[wave][digit] + rnk;
      if (MODE == 2) ((uint32_t*)sbuf)[slot] = (uint32_t)kvR[r];
      else           sbuf[slot] = kvR[r];
    }
  }
  __syncthreads();

  // ---- cnt is dead: reuse as adjArr ----
  int* adjArr = (int*)cnt;
  if (t < NB) adjArr[t] = adjv;
  __syncthreads();

  // ---- write out sequentially: digit runs are contiguous (64B lines) ----
  int validCount = min(TB, N - b * TB);
#pragma unroll
  for (int j = 0; j < RNDS; ++j) {
    int i = j * SCTH + t;
    if (i < validCount) {
      if (MODE == 0) {
        uint64_t kv = sbuf[i];
        int pos = adjArr[(uint32_t)kv & 511u] + i;
        out64[pos] = kv;                               // one 8B store (AoS)
      } else if (MODE == 1) {
        uint64_t kv = sbuf[i];
        uint32_t key = (uint32_t)kv, idxv = (uint32_t)(kv >> 32);
        int pos = adjArr[(key >> 9) & 511u] + i;
        out32[pos] = ((key >> 18) << IDX_BITS) | idxv;  // digit2<<22 | idx
      } else {
        uint32_t p = ((uint32_t*)sbuf)[i];
        int pos = adjArr[(p >> IDX_BITS) & 255u] + i;
        out32[pos] = p & IDX_MASK;
      }
    }
  }
}

// ---------------- launch ----------------
extern "C" void kernel_launch(void* const* d_in, const int* in_sizes, int n_in,
                              void* d_out, int out_size, void* d_ws, size_t ws_size,
                              hipStream_t stream) {
  const int4* coords = (const int4*)d_in[0];
  const void* ss = d_in[1];
  const int* shifts = (const int*)d_in[2];
  int N = in_sizes[0] / 4;
  int nblocks = (N + TILE - 1) / TILE;       // passes 0/1 tiles (489)
  int nblocks2 = (N + TILE2 - 1) / TILE2;    // pass-2 tiles (245)

  char* ws = (char*)d_ws;
  size_t off = 0;
  auto alloc = [&](size_t bytes) -> void* {
    void* p = ws + off;
    off += (bytes + 255) & ~(size_t)255;
    return p;
  };
  uint32_t* keys0  = (uint32_t*)alloc((size_t)N * 4);
  uint64_t* pairs1 = (uint64_t*)alloc((size_t)N * 8);
  uint32_t* packd  = (uint32_t*)alloc((size_t)N * 4);
  int*      hist   = (int*)alloc((size_t)512 * nblocks * 4);
  int*      digitTotals = (int*)alloc(512 * 4);

  // pass 0 (bits 0..8, 512 bins): keys only; vals implicit (val == idx)
  genkeys_hist<<<nblocks, THREADS, 0, stream>>>(coords, ss, shifts, keys0, hist, N);
  scan_blocks<<<512, 512, 0, stream>>>(hist, digitTotals, nblocks, 512);
  scatter_kernel<0><<<nblocks, SCTH, 0, stream>>>(
      keys0, nullptr, nullptr, pairs1, hist, digitTotals, N);

  // pass 1 (bits 9..17, 512 bins): AoS pairs in, packed (digit2<<22|idx) out
  hist_pairs<<<nblocks, THREADS, 0, stream>>>(pairs1, hist, N);
  scan_blocks<<<512, 512, 0, stream>>>(hist, digitTotals, nblocks, 512);
  scatter_kernel<1><<<nblocks, SCTH, 0, stream>>>(
      nullptr, pairs1, packd, nullptr, hist, digitTotals, N);

  // pass 2 (packed bits 22..29, 256 bins, TILE2=8192): idx lands in d_out
  hist_packd<<<nblocks2, THREADS, 0, stream>>>(packd, hist, N);
  scan_blocks<<<256, 512, 0, stream>>>(hist, digitTotals, nblocks2, 256);
  scatter_kernel<2><<<nblocks2, SCTH, 0, stream>>>(
      packd, nullptr, (uint32_t*)d_out, nullptr, hist, digitTotals, N);
}